// Round 17
// baseline (240.734 us; speedup 1.0000x reference)
//
#include <hip/hip_runtime.h>
#include <cstdint>
#include <cstddef>

typedef __attribute__((ext_vector_type(8))) short short8v;
typedef __attribute__((ext_vector_type(4))) float f32x4;
typedef __attribute__((ext_vector_type(16))) float f32x16;
typedef __attribute__((ext_vector_type(4))) unsigned int u32x4;
typedef unsigned short us;

#define GLL16(gsrc, ldst)                                                           \
  __builtin_amdgcn_global_load_lds((__attribute__((address_space(1))) void*)(gsrc), \
                                   (__attribute__((address_space(3))) void*)(ldst), \
                                   16, 0, 0)

#define MFMA32(a, b, c) __builtin_amdgcn_mfma_f32_32x32x16_bf16((a), (b), (c), 0, 0, 0)

static __device__ __forceinline__ us f2bf(float f) {
  unsigned int u = __float_as_uint(f);
  u += 0x7FFFu + ((u >> 16) & 1u);   // RNE; inputs finite
  return (us)(u >> 16);
}

static __device__ __forceinline__ unsigned int cvtpk_bf16(float lo, float hi) {
  unsigned int r;
  asm("v_cvt_pk_bf16_f32 %0, %1, %2" : "=v"(r) : "v"(lo), "v"(hi));
  return r;
}

// Build one PV A-fragment (16 kv) from S^T accumulator regs [B..B+7].
// [verified r8] swap(X,Z), swap(Y,W) -> words = 32x32x16 A layout (k=8*hi+j).
template <int B>
static __device__ __forceinline__ short8v pack_swap(const f32x16& p) {
  unsigned int X = cvtpk_bf16(p[B + 0], p[B + 1]);
  unsigned int Y = cvtpk_bf16(p[B + 2], p[B + 3]);
  unsigned int Z = cvtpk_bf16(p[B + 4], p[B + 5]);
  unsigned int W = cvtpk_bf16(p[B + 6], p[B + 7]);
  asm("v_permlane32_swap_b32 %0, %1" : "+v"(X), "+v"(Z));
  asm("v_permlane32_swap_b32 %0, %1" : "+v"(Y), "+v"(W));
  u32x4 f;
  f.x = X; f.y = Y; f.z = Z; f.w = W;
  return __builtin_bit_cast(short8v, f);
}

// cvt 8 fp32 (two float4) -> 4 u32 of bf16 pairs
static __device__ __forceinline__ u32x4 cvt8(const float4 a, const float4 b) {
  u32x4 u;
  u.x = cvtpk_bf16(a.x, a.y);
  u.y = cvtpk_bf16(a.z, a.w);
  u.z = cvtpk_bf16(b.x, b.y);
  u.w = cvtpk_bf16(b.z, b.w);
  return u;
}

// ---------------- gemm_qkv: fp32 A (x) and fp32 B (qkv_w), fused convert ------
// r15 structure with the staging map FIXED for bank-conflict-free LDS writes:
// granule map row=G&127, kslot=G>>7 -> ds_write dest is LINEAR in G (lane i
// writes byte 16*i: banks covered exactly once per 8-lane group, 0 conflicts
// — same pattern as gll16's internal write; r15/r16's row=G>>2 map was a
// 4-way write conflict, 5.5M cycles measured). Global source: 32 B/lane at
// row-stride — identical shape to r10's gll16 A-fetch (proven fine).
// 128x128 tile, 4 waves (2x2, 64x64), BK=32, 2 LDS buffers (32 KB).
// T14 split: loads issue at step top, cvt+ds_write after the MFMAs.
// XCD-swizzled blockIdx. Epilogue: q(*0.125*log2e)/k direct; v two-pass
// wave-private LDS transpose (r12/r15-proven).
__global__ __launch_bounds__(256, 3)
void gemm_qkv(const float* __restrict__ A32, const float* __restrict__ B32,
              int M, int N, int K,
              us* __restrict__ qout, us* __restrict__ kout, us* __restrict__ vtout)
{
  __shared__ us SH[2][2][128 * 32];   // [buf][A|B][kslot(4)][row(128)][8] = 32 KB

  const int tid  = threadIdx.x;
  const int lane = tid & 63;
  const int w    = tid >> 6;          // 0..3
  const int g    = lane >> 4;         // 0..3
  const int c    = lane & 15;
  const int wr   = w >> 1;            // 0..1 (M)
  const int wc   = w & 1;             // 0..1 (N)
  const int ntn  = N >> 7;            // 18

  const int nwg  = (M >> 7) * ntn;    // 1152
  const int cpx  = nwg >> 3;
  const int bid  = (blockIdx.x & 7) * cpx + (blockIdx.x >> 3);
  const int tm   = bid / ntn;
  const int tn   = bid - tm * ntn;
  const int row_a0 = tm * 128;
  const int col_b0 = tn * 128;

  f32x4 acc[4][4];
#pragma unroll
  for (int i = 0; i < 4; ++i)
#pragma unroll
    for (int j = 0; j < 4; ++j) acc[i][j] = (f32x4){0.f, 0.f, 0.f, 0.f};

  float4 ra[2][2], rb[2][2];   // staging regs: [granule][half], 32 VGPR

#define STAGE_LOAD(ks)                                                        \
  do {                                                                        \
    _Pragma("unroll")                                                         \
    for (int p = 0; p < 2; ++p) {                                             \
      int G = p * 256 + tid, row = G & 127, kslot = G >> 7;                   \
      const float* s = A32 + (size_t)(row_a0 + row) * K + (ks) * 32 + kslot * 8; \
      ra[p][0] = *(const float4*)s;  ra[p][1] = *(const float4*)(s + 4);      \
    }                                                                         \
    _Pragma("unroll")                                                         \
    for (int p = 0; p < 2; ++p) {                                             \
      int G = p * 256 + tid, row = G & 127, kslot = G >> 7;                   \
      const float* s = B32 + (size_t)(col_b0 + row) * K + (ks) * 32 + kslot * 8; \
      rb[p][0] = *(const float4*)s;  rb[p][1] = *(const float4*)(s + 4);      \
    }                                                                         \
  } while (0)

#define STAGE_WRITE(buf)                                                      \
  do {                                                                        \
    _Pragma("unroll")                                                         \
    for (int p = 0; p < 2; ++p) {                                             \
      int G = p * 256 + tid;                                                  \
      *(u32x4*)&SH[buf][0][G * 8] = cvt8(ra[p][0], ra[p][1]);                 \
      *(u32x4*)&SH[buf][1][G * 8] = cvt8(rb[p][0], rb[p][1]);                 \
    }                                                                         \
  } while (0)

  const int nt = K >> 5;   // 24
  STAGE_LOAD(0);
  STAGE_WRITE(0);
  __syncthreads();

  for (int t = 0; t < nt; ++t) {
    const int cur = t & 1;
    if (t + 1 < nt) STAGE_LOAD(t + 1);   // loads issue here; results used post-MFMA

    short8v af[4], bfr[4];
#pragma unroll
    for (int mi = 0; mi < 4; ++mi)
      af[mi] = *(const short8v*)&SH[cur][0][(g * 128 + wr * 64 + mi * 16 + c) * 8];
#pragma unroll
    for (int nj = 0; nj < 4; ++nj)
      bfr[nj] = *(const short8v*)&SH[cur][1][(g * 128 + wc * 64 + nj * 16 + c) * 8];
    __builtin_amdgcn_s_setprio(1);
#pragma unroll
    for (int mi = 0; mi < 4; ++mi)
#pragma unroll
      for (int nj = 0; nj < 4; ++nj)
        acc[mi][nj] = __builtin_amdgcn_mfma_f32_16x16x32_bf16(af[mi], bfr[nj], acc[mi][nj], 0, 0, 0);
    __builtin_amdgcn_s_setprio(0);

    if (t + 1 < nt) STAGE_WRITE(cur ^ 1);   // waitcnt for loads lands here
    __syncthreads();
  }
#undef STAGE_LOAD
#undef STAGE_WRITE

  const int rbase = row_a0 + wr * 64;
  const int cbase = col_b0 + wc * 64;
  if (cbase < 1536) {
    // ---- q / k: direct stores (32B-contiguous per 16 c-lanes) ----
#pragma unroll
    for (int mi = 0; mi < 4; ++mi)
#pragma unroll
      for (int nj = 0; nj < 4; ++nj)
#pragma unroll
        for (int r = 0; r < 4; ++r) {
          float v   = acc[mi][nj][r];
          int mrow  = rbase + mi * 16 + g * 4 + r;
          int d     = cbase + nj * 16 + c;
          int hh    = d < 768 ? (d >> 6) : ((d - 768) >> 6);
          int dh    = d & 63;
          int b     = mrow >> 11, n = mrow & 2047;
          size_t bh = (size_t)(b * 12 + hh);
          // q pre-scaled by SCALE*log2e so attn's S is in log2 units
          if (d < 768) qout[(bh * 2048 + n) * 64 + dh] = f2bf(v * 0.18033688f);
          else         kout[(bh * 2048 + n) * 64 + dh] = f2bf(v);
        }
  } else {
    // ---- v: TWO-PASS wave-private LDS transpose (r12/r15-proven) ----
    us* Lw = &SH[0][0][0] + w * (64 * 40);   // 5 KB/wave x4 = 20 KB <= 32 KB
    const int b   = rbase >> 11;
    const int nl0 = rbase & 2047;
    const int h2  = (cbase - 1536) >> 6;
    const size_t vrow0 = ((size_t)(b * 12 + h2)) * 64;
#pragma unroll
    for (int pass = 0; pass < 2; ++pass) {
#pragma unroll
      for (int mi2 = 0; mi2 < 2; ++mi2) {
        int mi = pass * 2 + mi2;
#pragma unroll
        for (int nj = 0; nj < 4; ++nj)
#pragma unroll
          for (int r = 0; r < 4; ++r)
            Lw[(nj * 16 + c) * 40 + mi2 * 16 + g * 4 + r] = f2bf(acc[mi][nj][r]);
      }
#pragma unroll
      for (int p = 0; p < 4; ++p) {
        int G   = p * 64 + lane;          // 256 granules: 64 d x 4 segs of 8 n
        int dl  = G >> 2;
        int seg = G & 3;
        short8v vv = *(const short8v*)&Lw[dl * 40 + seg * 8];
        *(short8v*)(vtout + (vrow0 + dl) * 2048 + nl0 + pass * 32 + seg * 8) = vv;
      }
    }
  }
}

// ---------------- gemm_proj: bf16 A (attn out, via gll) + fp32 B (proj_w) ----
__global__ __launch_bounds__(256, 3)
void gemm_proj(const us* __restrict__ A, const float* __restrict__ B32,
               int M, int N, int K,
               const float* __restrict__ bias, float* __restrict__ fout)
{
  __shared__ us SH[2][2][128 * 32];   // 32 KB

  const int tid  = threadIdx.x;
  const int lane = tid & 63;
  const int w    = tid >> 6;
  const int g    = lane >> 4;
  const int c    = lane & 15;
  const int wr   = w >> 1;
  const int wc   = w & 1;
  const int ntn  = N >> 7;            // 6

  const int nwg  = (M >> 7) * ntn;    // 384
  const int cpx  = nwg >> 3;
  const int bid  = (blockIdx.x & 7) * cpx + (blockIdx.x >> 3);
  const int tm   = bid / ntn;
  const int tn   = bid - tm * ntn;
  const int row_a0 = tm * 128;
  const int col_b0 = tn * 128;

  f32x4 acc[4][4];
#pragma unroll
  for (int i = 0; i < 4; ++i)
#pragma unroll
    for (int j = 0; j < 4; ++j) acc[i][j] = (f32x4){0.f, 0.f, 0.f, 0.f};

  float4 rb[2][2];

#define STAGE_A(buf, ks)                                                      \
  do {                                                                        \
    _Pragma("unroll")                                                         \
    for (int p = 0; p < 2; ++p) {                                             \
      int G = p * 256 + tid;                                                  \
      int kslot = G >> 7, row = G & 127;                                      \
      GLL16(A + (size_t)(row_a0 + row) * K + (ks) * 32 + kslot * 8,           \
            &SH[buf][0][G * 8]);                                              \
    }                                                                         \
  } while (0)

#define STAGE_B_LOAD(ks)                                                      \
  do {                                                                        \
    _Pragma("unroll")                                                         \
    for (int p = 0; p < 2; ++p) {                                             \
      int G = p * 256 + tid, row = G & 127, kslot = G >> 7;                   \
      const float* s = B32 + (size_t)(col_b0 + row) * K + (ks) * 32 + kslot * 8; \
      rb[p][0] = *(const float4*)s;  rb[p][1] = *(const float4*)(s + 4);      \
    }                                                                         \
  } while (0)

#define STAGE_B_WRITE(buf)                                                    \
  do {                                                                        \
    _Pragma("unroll")                                                         \
    for (int p = 0; p < 2; ++p) {                                             \
      int G = p * 256 + tid;                                                  \
      *(u32x4*)&SH[buf][1][G * 8] = cvt8(rb[p][0], rb[p][1]);                 \
    }                                                                         \
  } while (0)

  const int nt = K >> 5;   // 24
  STAGE_A(0, 0);
  STAGE_B_LOAD(0);
  STAGE_B_WRITE(0);
  __syncthreads();   // drains gll vmcnt + lgkm

  for (int t = 0; t < nt; ++t) {
    const int cur = t & 1;
    if (t + 1 < nt) { STAGE_A(cur ^ 1, t + 1); STAGE_B_LOAD(t + 1); }

    short8v af[4], bfr[4];
#pragma unroll
    for (int mi = 0; mi < 4; ++mi)
      af[mi] = *(const short8v*)&SH[cur][0][(g * 128 + wr * 64 + mi * 16 + c) * 8];
#pragma unroll
    for (int nj = 0; nj < 4; ++nj)
      bfr[nj] = *(const short8v*)&SH[cur][1][(g * 128 + wc * 64 + nj * 16 + c) * 8];
    __builtin_amdgcn_s_setprio(1);
#pragma unroll
    for (int mi = 0; mi < 4; ++mi)
#pragma unroll
      for (int nj = 0; nj < 4; ++nj)
        acc[mi][nj] = __builtin_amdgcn_mfma_f32_16x16x32_bf16(af[mi], bfr[nj], acc[mi][nj], 0, 0, 0);
    __builtin_amdgcn_s_setprio(0);

    if (t + 1 < nt) STAGE_B_WRITE(cur ^ 1);
    __syncthreads();
  }
#undef STAGE_A
#undef STAGE_B_LOAD
#undef STAGE_B_WRITE

  const int rbase = row_a0 + wr * 64;
  const int cbase = col_b0 + wc * 64;
#pragma unroll
  for (int mi = 0; mi < 4; ++mi)
#pragma unroll
    for (int nj = 0; nj < 4; ++nj) {
      int d = cbase + nj * 16 + c;
      float bv = bias[d];
#pragma unroll
      for (int r = 0; r < 4; ++r) {
        int mrow = rbase + mi * 16 + g * 4 + r;
        fout[(size_t)mrow * N + d] = acc[mi][nj][r] + bv;
      }
    }
}

// ---------------- flash attention v6 (r9-verified, unchanged) ----------------
__global__ __launch_bounds__(256, 3)
void attn_fwd(const us* __restrict__ Qg, const us* __restrict__ Kg,
              const us* __restrict__ Vg, us* __restrict__ Og)
{
  __shared__ us Ks[2][8 * 64 * 8];   // [dslot(8)][kv(64)][8 d]
  __shared__ us Vs[2][8 * 64 * 8];   // [kvslot(8)][dh(64)][8 kv]

  const int tid  = threadIdx.x;
  const int lane = tid & 63;
  const int w    = tid >> 6;
  const int q31  = lane & 31;
  const int hi   = lane >> 5;

  const int lin = blockIdx.x;        // 768 = 8 xcd * 6 bh * 16 qt
  const int xcd = lin & 7;
  const int idx = lin >> 3;
  const int bh  = xcd * 6 + (idx >> 4);
  const int qt  = idx & 15;
  const int b   = bh / 12;
  const int h   = bh - b * 12;

  const size_t qrow0 = (size_t)bh * 2048 + qt * 128 + w * 32;

  short8v qf[4];
#pragma unroll
  for (int dc = 0; dc < 4; ++dc)
    qf[dc] = *(const short8v*)(Qg + (qrow0 + q31) * 64 + dc * 16 + hi * 8);

  short8v ones;
#pragma unroll
  for (int j = 0; j < 8; ++j) ones[j] = (short)0x3F80;   // bf16 1.0

  f32x16 o0, o1, ls, z16;
#pragma unroll
  for (int r = 0; r < 16; ++r) { o0[r] = 0.f; o1[r] = 0.f; ls[r] = 0.f; z16[r] = 0.f; }

  const size_t kbase = (size_t)bh * 2048 * 64;
  const size_t vbase = (size_t)bh * 64 * 2048;

#define STAGE_KV(buf, kv0)                                             \
  do {                                                                 \
    _Pragma("unroll")                                                  \
    for (int p = 0; p < 2; ++p) {                                      \
      int G = p * 256 + tid;                                           \
      int kslot = G >> 6, row = G & 63;                                \
      GLL16(Kg + kbase + (size_t)((kv0) + row) * 64 + kslot * 8,       \
            &Ks[buf][(p * 256 + w * 64) * 8]);                         \
    }                                                                  \
    _Pragma("unroll")                                                  \
    for (int p = 0; p < 2; ++p) {                                      \
      int G = p * 256 + tid;                                           \
      int kvslot = G >> 6, dh = G & 63;                                \
      GLL16(Vg + vbase + (size_t)dh * 2048 + (kv0) + kvslot * 8,       \
            &Vs[buf][(p * 256 + w * 64) * 8]);                         \
    }                                                                  \
  } while (0)

  STAGE_KV(0, 0);
  __syncthreads();

  for (int t = 0; t < 32; ++t) {
    const int cur = t & 1;
    if (t < 31) STAGE_KV(cur ^ 1, (t + 1) * 64);

    // ---- S^T = K Q^T (log2 units): s0 = kv 0..31, s1 = kv 32..63 ----
    f32x16 s0, s1;
    __builtin_amdgcn_s_setprio(1);
    {
      const us* kb = &Ks[cur][(hi * 64 + q31) * 8];
      short8v kf0 = *(const short8v*)kb;
      short8v kf1 = *(const short8v*)(kb + 32 * 8);
      s0 = MFMA32(kf0, qf[0], z16);
      s1 = MFMA32(kf1, qf[0], z16);
    }
#pragma unroll
    for (int dc = 1; dc < 4; ++dc) {
      const us* kb = &Ks[cur][((dc * 2 + hi) * 64 + q31) * 8];
      short8v kf0 = *(const short8v*)kb;
      short8v kf1 = *(const short8v*)(kb + 32 * 8);
      s0 = MFMA32(kf0, qf[dc], s0);
      s1 = MFMA32(kf1, qf[dc], s1);
    }
    __builtin_amdgcn_s_setprio(0);

    // ---- P = exp2(S) in-register ----
#pragma unroll
    for (int r = 0; r < 16; ++r) {
      s0[r] = __builtin_amdgcn_exp2f(s0[r]);
      s1[r] = __builtin_amdgcn_exp2f(s1[r]);
    }

    // ---- pack to bf16 A-frags (no LDS) ----
    short8v pa[4];
    pa[0] = pack_swap<0>(s0);   // kv  0..15
    pa[1] = pack_swap<8>(s0);   // kv 16..31
    pa[2] = pack_swap<0>(s1);   // kv 32..47
    pa[3] = pack_swap<8>(s1);   // kv 48..63

    // ---- O += P V ; ls += P 1 ----
    __builtin_amdgcn_s_setprio(1);
#pragma unroll
    for (int kc = 0; kc < 4; ++kc) {
      const us* vb = &Vs[cur][((kc * 2 + hi) * 64 + q31) * 8];
      short8v vf0 = *(const short8v*)vb;            // d  0..31
      short8v vf1 = *(const short8v*)(vb + 32 * 8); // d 32..63
      o0 = MFMA32(pa[kc], vf0, o0);
      o1 = MFMA32(pa[kc], vf1, o1);
      ls = MFMA32(pa[kc], ones, ls);
    }
    __builtin_amdgcn_s_setprio(0);

    __syncthreads();
  }
#undef STAGE_KV

  const int n0w = qt * 128 + w * 32;
#pragma unroll
  for (int r = 0; r < 16; ++r) {
    float iv = 1.0f / ls[r];
    int n = n0w + (r & 3) + 8 * (r >> 2) + 4 * hi;
    size_t rowbase = ((size_t)b * 2048 + n) * 768 + h * 64 + q31;
    Og[rowbase]      = f2bf(o0[r] * iv);
    Og[rowbase + 32] = f2bf(o1[r] * iv);
  }
}

// ---------------- launch ----------------
extern "C" void kernel_launch(void* const* d_in, const int* in_sizes, int n_in,
                              void* d_out, int out_size, void* d_ws, size_t ws_size,
                              hipStream_t stream)
{
  const float* x      = (const float*)d_in[0];
  const float* qkv_w  = (const float*)d_in[1];
  const float* proj_w = (const float*)d_in[2];
  const float* proj_b = (const float*)d_in[3];

  char* ws = (char*)d_ws;
  const size_t SZ_AO   = (size_t)8192 * 768 * 2;   // attn output (bf16)
  const size_t SZ_HEAD = (size_t)48 * 2048 * 64;   // elements per q/k/vt buffer

  us* attn_o = (us*)(ws);
  us* q_bf   = (us*)(ws + SZ_AO);
  us* k_bf   = q_bf + SZ_HEAD;
  us* vt_bf  = k_bf + SZ_HEAD;

  gemm_qkv<<<64 * 18, 256, 0, stream>>>(x, qkv_w, 8192, 2304, 768,
                                        q_bf, k_bf, vt_bf);

  attn_fwd<<<768, 256, 0, stream>>>(q_bf, k_bf, vt_bf, attn_o);

  gemm_proj<<<64 * 6, 256, 0, stream>>>(attn_o, proj_w, 8192, 768, 768,
                                        proj_b, (float*)d_out);
}

// Round 18
// 152.660 us; speedup vs baseline: 1.5769x; 1.5769x over previous
//
#include <hip/hip_runtime.h>
#include <cstdint>
#include <cstddef>

typedef __attribute__((ext_vector_type(8))) short short8v;
typedef __attribute__((ext_vector_type(4))) float f32x4;
typedef __attribute__((ext_vector_type(16))) float f32x16;
typedef __attribute__((ext_vector_type(4))) unsigned int u32x4;
typedef unsigned short us;

#define GLL16(gsrc, ldst)                                                           \
  __builtin_amdgcn_global_load_lds((__attribute__((address_space(1))) void*)(gsrc), \
                                   (__attribute__((address_space(3))) void*)(ldst), \
                                   16, 0, 0)

#define MFMA32(a, b, c) __builtin_amdgcn_mfma_f32_32x32x16_bf16((a), (b), (c), 0, 0, 0)

static __device__ __forceinline__ us f2bf(float f) {
  unsigned int u = __float_as_uint(f);
  u += 0x7FFFu + ((u >> 16) & 1u);   // RNE; inputs finite
  return (us)(u >> 16);
}

static __device__ __forceinline__ unsigned int cvtpk_bf16(float lo, float hi) {
  unsigned int r;
  asm("v_cvt_pk_bf16_f32 %0, %1, %2" : "=v"(r) : "v"(lo), "v"(hi));
  return r;
}

// Build one PV A-fragment (16 kv) from S^T accumulator regs [B..B+7].
// [verified r8] swap(X,Z), swap(Y,W) -> words = 32x32x16 A layout (k=8*hi+j).
template <int B>
static __device__ __forceinline__ short8v pack_swap(const f32x16& p) {
  unsigned int X = cvtpk_bf16(p[B + 0], p[B + 1]);
  unsigned int Y = cvtpk_bf16(p[B + 2], p[B + 3]);
  unsigned int Z = cvtpk_bf16(p[B + 4], p[B + 5]);
  unsigned int W = cvtpk_bf16(p[B + 6], p[B + 7]);
  asm("v_permlane32_swap_b32 %0, %1" : "+v"(X), "+v"(Z));
  asm("v_permlane32_swap_b32 %0, %1" : "+v"(Y), "+v"(W));
  u32x4 f;
  f.x = X; f.y = Y; f.z = Z; f.w = W;
  return __builtin_bit_cast(short8v, f);
}

// cvt 8 fp32 (two float4) -> 4 u32 of bf16 pairs
static __device__ __forceinline__ u32x4 cvt8(const float4 a, const float4 b) {
  u32x4 u;
  u.x = cvtpk_bf16(a.x, a.y);
  u.y = cvtpk_bf16(a.z, a.w);
  u.z = cvtpk_bf16(b.x, b.y);
  u.w = cvtpk_bf16(b.z, b.w);
  return u;
}

// ---------------- gemm_qkv: fp32 A (x) and fp32 B (qkv_w), fused convert ------
// r15 structure (155.5 us total, best) + T2 XOR swizzle on the staged LDS:
//  - global map row=G>>2, kslot=G&3 (COALESCED: 4 lanes cover 128B; r17's
//    row=G&127 map was strided -> FETCH 3x, dur 2.4x)
//  - LDS us-index = (kslot*128+row)*8 ^ (kslot<<4)  [byte-XOR kslot<<5]:
//    write quarter-wave = rows x kslots tiles all 32 banks exactly 2x = free
//    (r15's unswizzled write was a 4-way conflict, 11M cyc measured r16);
//    frag READ gets the identical XOR (g = kslot) -> both-sides consistent
//    (rule: swizzle both sides or neither), still 2 lanes/bank = free.
// 128x128 tile, 4 waves (2x2, 64x64), BK=32, 2 LDS buffers (32 KB).
// T14 split: loads issue at step top, cvt+ds_write after the MFMAs.
// XCD-swizzled blockIdx. Epilogue: q(*0.125*log2e)/k direct; v two-pass
// wave-private LDS transpose (r12/r15-proven).
__global__ __launch_bounds__(256, 3)
void gemm_qkv(const float* __restrict__ A32, const float* __restrict__ B32,
              int M, int N, int K,
              us* __restrict__ qout, us* __restrict__ kout, us* __restrict__ vtout)
{
  __shared__ us SH[2][2][128 * 32];   // [buf][A|B][kslot(4)][row(128)][8] = 32 KB

  const int tid  = threadIdx.x;
  const int lane = tid & 63;
  const int w    = tid >> 6;          // 0..3
  const int g    = lane >> 4;         // 0..3
  const int c    = lane & 15;
  const int wr   = w >> 1;            // 0..1 (M)
  const int wc   = w & 1;             // 0..1 (N)
  const int ntn  = N >> 7;            // 18

  const int nwg  = (M >> 7) * ntn;    // 1152
  const int cpx  = nwg >> 3;
  const int bid  = (blockIdx.x & 7) * cpx + (blockIdx.x >> 3);
  const int tm   = bid / ntn;
  const int tn   = bid - tm * ntn;
  const int row_a0 = tm * 128;
  const int col_b0 = tn * 128;

  f32x4 acc[4][4];
#pragma unroll
  for (int i = 0; i < 4; ++i)
#pragma unroll
    for (int j = 0; j < 4; ++j) acc[i][j] = (f32x4){0.f, 0.f, 0.f, 0.f};

  float4 ra[2][2], rb[2][2];   // staging regs: [granule][half], 32 VGPR

#define STAGE_LOAD(ks)                                                        \
  do {                                                                        \
    _Pragma("unroll")                                                         \
    for (int p = 0; p < 2; ++p) {                                             \
      int G = p * 256 + tid, row = G >> 2, kslot = G & 3;                     \
      const float* s = A32 + (size_t)(row_a0 + row) * K + (ks) * 32 + kslot * 8; \
      ra[p][0] = *(const float4*)s;  ra[p][1] = *(const float4*)(s + 4);      \
    }                                                                         \
    _Pragma("unroll")                                                         \
    for (int p = 0; p < 2; ++p) {                                             \
      int G = p * 256 + tid, row = G >> 2, kslot = G & 3;                     \
      const float* s = B32 + (size_t)(col_b0 + row) * K + (ks) * 32 + kslot * 8; \
      rb[p][0] = *(const float4*)s;  rb[p][1] = *(const float4*)(s + 4);      \
    }                                                                         \
  } while (0)

#define STAGE_WRITE(buf)                                                      \
  do {                                                                        \
    _Pragma("unroll")                                                         \
    for (int p = 0; p < 2; ++p) {                                             \
      int G = p * 256 + tid, row = G >> 2, kslot = G & 3;                     \
      int I = ((kslot * 128 + row) * 8) ^ (kslot << 4);                       \
      *(u32x4*)&SH[buf][0][I] = cvt8(ra[p][0], ra[p][1]);                     \
      *(u32x4*)&SH[buf][1][I] = cvt8(rb[p][0], rb[p][1]);                     \
    }                                                                         \
  } while (0)

  const int nt = K >> 5;   // 24
  STAGE_LOAD(0);
  STAGE_WRITE(0);
  __syncthreads();

  const int rxor = g << 4;   // frag-read XOR: g IS the kslot of the fragment

  for (int t = 0; t < nt; ++t) {
    const int cur = t & 1;
    if (t + 1 < nt) STAGE_LOAD(t + 1);   // loads issue here; results used post-MFMA

    short8v af[4], bfr[4];
#pragma unroll
    for (int mi = 0; mi < 4; ++mi)
      af[mi] = *(const short8v*)&SH[cur][0][((g * 128 + wr * 64 + mi * 16 + c) * 8) ^ rxor];
#pragma unroll
    for (int nj = 0; nj < 4; ++nj)
      bfr[nj] = *(const short8v*)&SH[cur][1][((g * 128 + wc * 64 + nj * 16 + c) * 8) ^ rxor];
    __builtin_amdgcn_s_setprio(1);
#pragma unroll
    for (int mi = 0; mi < 4; ++mi)
#pragma unroll
      for (int nj = 0; nj < 4; ++nj)
        acc[mi][nj] = __builtin_amdgcn_mfma_f32_16x16x32_bf16(af[mi], bfr[nj], acc[mi][nj], 0, 0, 0);
    __builtin_amdgcn_s_setprio(0);

    if (t + 1 < nt) STAGE_WRITE(cur ^ 1);   // waitcnt for loads lands here
    __syncthreads();
  }
#undef STAGE_LOAD
#undef STAGE_WRITE

  const int rbase = row_a0 + wr * 64;
  const int cbase = col_b0 + wc * 64;
  if (cbase < 1536) {
    // ---- q / k: direct stores (32B-contiguous per 16 c-lanes) ----
#pragma unroll
    for (int mi = 0; mi < 4; ++mi)
#pragma unroll
      for (int nj = 0; nj < 4; ++nj)
#pragma unroll
        for (int r = 0; r < 4; ++r) {
          float v   = acc[mi][nj][r];
          int mrow  = rbase + mi * 16 + g * 4 + r;
          int d     = cbase + nj * 16 + c;
          int hh    = d < 768 ? (d >> 6) : ((d - 768) >> 6);
          int dh    = d & 63;
          int b     = mrow >> 11, n = mrow & 2047;
          size_t bh = (size_t)(b * 12 + hh);
          // q pre-scaled by SCALE*log2e so attn's S is in log2 units
          if (d < 768) qout[(bh * 2048 + n) * 64 + dh] = f2bf(v * 0.18033688f);
          else         kout[(bh * 2048 + n) * 64 + dh] = f2bf(v);
        }
  } else {
    // ---- v: TWO-PASS wave-private LDS transpose (r12/r15-proven) ----
    us* Lw = &SH[0][0][0] + w * (64 * 40);   // 5 KB/wave x4 = 20 KB <= 32 KB
    const int b   = rbase >> 11;
    const int nl0 = rbase & 2047;
    const int h2  = (cbase - 1536) >> 6;
    const size_t vrow0 = ((size_t)(b * 12 + h2)) * 64;
#pragma unroll
    for (int pass = 0; pass < 2; ++pass) {
#pragma unroll
      for (int mi2 = 0; mi2 < 2; ++mi2) {
        int mi = pass * 2 + mi2;
#pragma unroll
        for (int nj = 0; nj < 4; ++nj)
#pragma unroll
          for (int r = 0; r < 4; ++r)
            Lw[(nj * 16 + c) * 40 + mi2 * 16 + g * 4 + r] = f2bf(acc[mi][nj][r]);
      }
#pragma unroll
      for (int p = 0; p < 4; ++p) {
        int G   = p * 64 + lane;          // 256 granules: 64 d x 4 segs of 8 n
        int dl  = G >> 2;
        int seg = G & 3;
        short8v vv = *(const short8v*)&Lw[dl * 40 + seg * 8];
        *(short8v*)(vtout + (vrow0 + dl) * 2048 + nl0 + pass * 32 + seg * 8) = vv;
      }
    }
  }
}

// ---------------- gemm_proj: bf16 A (attn out, via gll) + fp32 B (proj_w) ----
// A buffer gll16-linear (reads UNswizzled); B reg-staged with the same
// both-sides XOR swizzle as gemm_qkv.
__global__ __launch_bounds__(256, 3)
void gemm_proj(const us* __restrict__ A, const float* __restrict__ B32,
               int M, int N, int K,
               const float* __restrict__ bias, float* __restrict__ fout)
{
  __shared__ us SH[2][2][128 * 32];   // 32 KB

  const int tid  = threadIdx.x;
  const int lane = tid & 63;
  const int w    = tid >> 6;
  const int g    = lane >> 4;
  const int c    = lane & 15;
  const int wr   = w >> 1;
  const int wc   = w & 1;
  const int ntn  = N >> 7;            // 6

  const int nwg  = (M >> 7) * ntn;    // 384
  const int cpx  = nwg >> 3;
  const int bid  = (blockIdx.x & 7) * cpx + (blockIdx.x >> 3);
  const int tm   = bid / ntn;
  const int tn   = bid - tm * ntn;
  const int row_a0 = tm * 128;
  const int col_b0 = tn * 128;

  f32x4 acc[4][4];
#pragma unroll
  for (int i = 0; i < 4; ++i)
#pragma unroll
    for (int j = 0; j < 4; ++j) acc[i][j] = (f32x4){0.f, 0.f, 0.f, 0.f};

  float4 rb[2][2];

#define STAGE_A(buf, ks)                                                      \
  do {                                                                        \
    _Pragma("unroll")                                                         \
    for (int p = 0; p < 2; ++p) {                                             \
      int G = p * 256 + tid;                                                  \
      int kslot = G >> 7, row = G & 127;                                      \
      GLL16(A + (size_t)(row_a0 + row) * K + (ks) * 32 + kslot * 8,           \
            &SH[buf][0][G * 8]);                                              \
    }                                                                         \
  } while (0)

#define STAGE_B_LOAD(ks)                                                      \
  do {                                                                        \
    _Pragma("unroll")                                                         \
    for (int p = 0; p < 2; ++p) {                                             \
      int G = p * 256 + tid, row = G >> 2, kslot = G & 3;                     \
      const float* s = B32 + (size_t)(col_b0 + row) * K + (ks) * 32 + kslot * 8; \
      rb[p][0] = *(const float4*)s;  rb[p][1] = *(const float4*)(s + 4);      \
    }                                                                         \
  } while (0)

#define STAGE_B_WRITE(buf)                                                    \
  do {                                                                        \
    _Pragma("unroll")                                                         \
    for (int p = 0; p < 2; ++p) {                                             \
      int G = p * 256 + tid, row = G >> 2, kslot = G & 3;                     \
      int I = ((kslot * 128 + row) * 8) ^ (kslot << 4);                       \
      *(u32x4*)&SH[buf][1][I] = cvt8(rb[p][0], rb[p][1]);                     \
    }                                                                         \
  } while (0)

  const int nt = K >> 5;   // 24
  STAGE_A(0, 0);
  STAGE_B_LOAD(0);
  STAGE_B_WRITE(0);
  __syncthreads();   // drains gll vmcnt + lgkm

  const int rxor = g << 4;

  for (int t = 0; t < nt; ++t) {
    const int cur = t & 1;
    if (t + 1 < nt) { STAGE_A(cur ^ 1, t + 1); STAGE_B_LOAD(t + 1); }

    short8v af[4], bfr[4];
#pragma unroll
    for (int mi = 0; mi < 4; ++mi)
      af[mi] = *(const short8v*)&SH[cur][0][(g * 128 + wr * 64 + mi * 16 + c) * 8];
#pragma unroll
    for (int nj = 0; nj < 4; ++nj)
      bfr[nj] = *(const short8v*)&SH[cur][1][((g * 128 + wc * 64 + nj * 16 + c) * 8) ^ rxor];
    __builtin_amdgcn_s_setprio(1);
#pragma unroll
    for (int mi = 0; mi < 4; ++mi)
#pragma unroll
      for (int nj = 0; nj < 4; ++nj)
        acc[mi][nj] = __builtin_amdgcn_mfma_f32_16x16x32_bf16(af[mi], bfr[nj], acc[mi][nj], 0, 0, 0);
    __builtin_amdgcn_s_setprio(0);

    if (t + 1 < nt) STAGE_B_WRITE(cur ^ 1);
    __syncthreads();
  }
#undef STAGE_A
#undef STAGE_B_LOAD
#undef STAGE_B_WRITE

  const int rbase = row_a0 + wr * 64;
  const int cbase = col_b0 + wc * 64;
#pragma unroll
  for (int mi = 0; mi < 4; ++mi)
#pragma unroll
    for (int nj = 0; nj < 4; ++nj) {
      int d = cbase + nj * 16 + c;
      float bv = bias[d];
#pragma unroll
      for (int r = 0; r < 4; ++r) {
        int mrow = rbase + mi * 16 + g * 4 + r;
        fout[(size_t)mrow * N + d] = acc[mi][nj][r] + bv;
      }
    }
}

// ---------------- flash attention v6 (r9-verified, unchanged) ----------------
__global__ __launch_bounds__(256, 3)
void attn_fwd(const us* __restrict__ Qg, const us* __restrict__ Kg,
              const us* __restrict__ Vg, us* __restrict__ Og)
{
  __shared__ us Ks[2][8 * 64 * 8];   // [dslot(8)][kv(64)][8 d]
  __shared__ us Vs[2][8 * 64 * 8];   // [kvslot(8)][dh(64)][8 kv]

  const int tid  = threadIdx.x;
  const int lane = tid & 63;
  const int w    = tid >> 6;
  const int q31  = lane & 31;
  const int hi   = lane >> 5;

  const int lin = blockIdx.x;        // 768 = 8 xcd * 6 bh * 16 qt
  const int xcd = lin & 7;
  const int idx = lin >> 3;
  const int bh  = xcd * 6 + (idx >> 4);
  const int qt  = idx & 15;
  const int b   = bh / 12;
  const int h   = bh - b * 12;

  const size_t qrow0 = (size_t)bh * 2048 + qt * 128 + w * 32;

  short8v qf[4];
#pragma unroll
  for (int dc = 0; dc < 4; ++dc)
    qf[dc] = *(const short8v*)(Qg + (qrow0 + q31) * 64 + dc * 16 + hi * 8);

  short8v ones;
#pragma unroll
  for (int j = 0; j < 8; ++j) ones[j] = (short)0x3F80;   // bf16 1.0

  f32x16 o0, o1, ls, z16;
#pragma unroll
  for (int r = 0; r < 16; ++r) { o0[r] = 0.f; o1[r] = 0.f; ls[r] = 0.f; z16[r] = 0.f; }

  const size_t kbase = (size_t)bh * 2048 * 64;
  const size_t vbase = (size_t)bh * 64 * 2048;

#define STAGE_KV(buf, kv0)                                             \
  do {                                                                 \
    _Pragma("unroll")                                                  \
    for (int p = 0; p < 2; ++p) {                                      \
      int G = p * 256 + tid;                                           \
      int kslot = G >> 6, row = G & 63;                                \
      GLL16(Kg + kbase + (size_t)((kv0) + row) * 64 + kslot * 8,       \
            &Ks[buf][(p * 256 + w * 64) * 8]);                         \
    }                                                                  \
    _Pragma("unroll")                                                  \
    for (int p = 0; p < 2; ++p) {                                      \
      int G = p * 256 + tid;                                           \
      int kvslot = G >> 6, dh = G & 63;                                \
      GLL16(Vg + vbase + (size_t)dh * 2048 + (kv0) + kvslot * 8,       \
            &Vs[buf][(p * 256 + w * 64) * 8]);                         \
    }                                                                  \
  } while (0)

  STAGE_KV(0, 0);
  __syncthreads();

  for (int t = 0; t < 32; ++t) {
    const int cur = t & 1;
    if (t < 31) STAGE_KV(cur ^ 1, (t + 1) * 64);

    // ---- S^T = K Q^T (log2 units): s0 = kv 0..31, s1 = kv 32..63 ----
    f32x16 s0, s1;
    __builtin_amdgcn_s_setprio(1);
    {
      const us* kb = &Ks[cur][(hi * 64 + q31) * 8];
      short8v kf0 = *(const short8v*)kb;
      short8v kf1 = *(const short8v*)(kb + 32 * 8);
      s0 = MFMA32(kf0, qf[0], z16);
      s1 = MFMA32(kf1, qf[0], z16);
    }
#pragma unroll
    for (int dc = 1; dc < 4; ++dc) {
      const us* kb = &Ks[cur][((dc * 2 + hi) * 64 + q31) * 8];
      short8v kf0 = *(const short8v*)kb;
      short8v kf1 = *(const short8v*)(kb + 32 * 8);
      s0 = MFMA32(kf0, qf[dc], s0);
      s1 = MFMA32(kf1, qf[dc], s1);
    }
    __builtin_amdgcn_s_setprio(0);

    // ---- P = exp2(S) in-register ----
#pragma unroll
    for (int r = 0; r < 16; ++r) {
      s0[r] = __builtin_amdgcn_exp2f(s0[r]);
      s1[r] = __builtin_amdgcn_exp2f(s1[r]);
    }

    // ---- pack to bf16 A-frags (no LDS) ----
    short8v pa[4];
    pa[0] = pack_swap<0>(s0);   // kv  0..15
    pa[1] = pack_swap<8>(s0);   // kv 16..31
    pa[2] = pack_swap<0>(s1);   // kv 32..47
    pa[3] = pack_swap<8>(s1);   // kv 48..63

    // ---- O += P V ; ls += P 1 ----
    __builtin_amdgcn_s_setprio(1);
#pragma unroll
    for (int kc = 0; kc < 4; ++kc) {
      const us* vb = &Vs[cur][((kc * 2 + hi) * 64 + q31) * 8];
      short8v vf0 = *(const short8v*)vb;            // d  0..31
      short8v vf1 = *(const short8v*)(vb + 32 * 8); // d 32..63
      o0 = MFMA32(pa[kc], vf0, o0);
      o1 = MFMA32(pa[kc], vf1, o1);
      ls = MFMA32(pa[kc], ones, ls);
    }
    __builtin_amdgcn_s_setprio(0);

    __syncthreads();
  }
#undef STAGE_KV

  const int n0w = qt * 128 + w * 32;
#pragma unroll
  for (int r = 0; r < 16; ++r) {
    float iv = 1.0f / ls[r];
    int n = n0w + (r & 3) + 8 * (r >> 2) + 4 * hi;
    size_t rowbase = ((size_t)b * 2048 + n) * 768 + h * 64 + q31;
    Og[rowbase]      = f2bf(o0[r] * iv);
    Og[rowbase + 32] = f2bf(o1[r] * iv);
  }
}

// ---------------- launch ----------------
extern "C" void kernel_launch(void* const* d_in, const int* in_sizes, int n_in,
                              void* d_out, int out_size, void* d_ws, size_t ws_size,
                              hipStream_t stream)
{
  const float* x      = (const float*)d_in[0];
  const float* qkv_w  = (const float*)d_in[1];
  const float* proj_w = (const float*)d_in[2];
  const float* proj_b = (const float*)d_in[3];

  char* ws = (char*)d_ws;
  const size_t SZ_AO   = (size_t)8192 * 768 * 2;   // attn output (bf16)
  const size_t SZ_HEAD = (size_t)48 * 2048 * 64;   // elements per q/k/vt buffer

  us* attn_o = (us*)(ws);
  us* q_bf   = (us*)(ws + SZ_AO);
  us* k_bf   = q_bf + SZ_HEAD;
  us* vt_bf  = k_bf + SZ_HEAD;

  gemm_qkv<<<64 * 18, 256, 0, stream>>>(x, qkv_w, 8192, 2304, 768,
                                        q_bf, k_bf, vt_bf);

  attn_fwd<<<768, 256, 0, stream>>>(q_bf, k_bf, vt_bf, attn_o);

  gemm_proj<<<64 * 6, 256, 0, stream>>>(attn_o, proj_w, 8192, 768, 768,
                                        proj_b, (float*)d_out);
}